// Round 8
// baseline (5006.192 us; speedup 1.0000x reference)
//
#include <hip/hip_runtime.h>
#include <math.h>

#define TSTEPS 512
#define BN 4096
#define NBLK 64
#define NTHR 576      // 9 waves: wave 0 = updater, waves 1..8 = gather waves
#define NPB 64        // neurons per block
#define NGW 8         // gather waves
#define ESTRIDE 16    // u64s per mailbox entry: one 128-B line per block

typedef unsigned long long u64;

__device__ __forceinline__ u64 ld_agent(const u64* p) {
    return __hip_atomic_load(p, __ATOMIC_RELAXED, __HIP_MEMORY_SCOPE_AGENT);
}
__device__ __forceinline__ void st_agent(u64* p, u64 v) {
    __hip_atomic_store(p, v, __ATOMIC_RELAXED, __HIP_MEMORY_SCOPE_AGENT);
}
__device__ __forceinline__ void st_flag(unsigned* p, unsigned v) {
    __hip_atomic_store(p, v, __ATOMIC_RELEASE, __HIP_MEMORY_SCOPE_WORKGROUP);
}
__device__ __forceinline__ unsigned ld_flag(const unsigned* p) {
    return __hip_atomic_load(p, __ATOMIC_ACQUIRE, __HIP_MEMORY_SCOPE_WORKGROUP);
}

// Persistent kernel, 64 blocks x 576 threads (9 waves).
//  wave 0   : pure updater. Spins on 8 LDS flags, combines the 8 per-wave
//             partials in a fixed tree, updates 64 neurons, publishes the
//             block's spike ballot as 2 tagged mailbox words.
//  waves 1-8: ARRIVAL-DRIVEN gather. Each wave owns 8 mailbox entries
//             (8 lanes per entry poll its 2 tagged words). The moment an
//             entry arrives, the whole wave gathers its active columns
//             (mask64 broadcast by shuffle; set bits walked in ascending
//             order; coalesced 64-lane column loads of mask-scaled wT) into
//             that entry's register accumulator -- overlapping the wait for
//             straggler entries. Accumulators combine in a FIXED 8-leaf
//             tree, so arithmetic is deterministic regardless of arrival
//             order. No prefix scan, no LDS column list, no block barrier.
// Race-freedom: publish(t+1) requires wave0 seen all flags(t) => all gather
// reads of mailbox(t) done; 2-parity mailbox + 4-deep partials ring.
template<bool TR>
__global__ __launch_bounds__(NTHR, 1)
void glif_kernel(const float* __restrict__ x_seq, const float* __restrict__ w,
                 const float* __restrict__ b_in, const float* __restrict__ v0,
                 const float* __restrict__ Ia0, const float* __restrict__ vth_in,
                 const float* __restrict__ vrst_in, const float* __restrict__ vrest_in,
                 const float* __restrict__ cm_in, const float* __restrict__ tau_in,
                 const float* __restrict__ k_in, const float* __restrict__ asc_in,
                 const float* __restrict__ mask_in,
                 float* __restrict__ out_s, float* __restrict__ out_v,
                 float* __restrict__ out_vf, float* __restrict__ out_if,
                 u64* __restrict__ sbuf, unsigned* __restrict__ bar,
                 float* __restrict__ wT)
{
    __shared__ float    tile[64][65];          // transpose staging (phase 0)
    __shared__ float    partials[4][NGW][64];  // 4-deep ring of GEMV partials
    __shared__ unsigned flags[NGW];            // monotonic step tags

    const int blk = blockIdx.x;
    const int tid = threadIdx.x;
    const int n0 = blk * NPB;
    const int wv = tid >> 6;                   // wave 0..8
    const int ln = tid & 63;

    // ---- Phase 0: transpose w -> wT, folding mask into columns
    // (w[n][j]*mask[j] rounds identically to the reference product with s=mask)
    if (TR) {
        for (int tt = 0; tt < 64; ++tt) {
            int tile_id = blk + tt * NBLK;     // 4096 tiles of 64x64
            int ti = tile_id >> 6, tj = tile_id & 63;
            if (tid < 512) {
                int c = tid & 63, r0 = tid >> 6;
#pragma unroll
                for (int rr = 0; rr < 8; ++rr) {
                    int r = r0 + rr * 8;
                    tile[r][c] = w[(size_t)(ti * 64 + r) * BN + tj * 64 + c];
                }
            }
            __syncthreads();
            if (tid < 512) {
                int rw = tid & 63, c0 = tid >> 6;
#pragma unroll
                for (int cc = 0; cc < 8; ++cc) {
                    int cw = c0 + cc * 8;
                    float mcol = mask_in[tj * 64 + cw];
                    wT[(size_t)(tj * 64 + cw) * BN + ti * 64 + rw] = tile[rw][cw] * mcol;
                }
            }
            __syncthreads();
        }
    }

    if (tid < NGW) flags[tid] = 0;

    // ---- single grid barrier: wT complete before step loop
    __syncthreads();
    if (tid == 0) {
        __threadfence();
        __hip_atomic_fetch_add(bar, 1u, __ATOMIC_ACQ_REL, __HIP_MEMORY_SCOPE_AGENT);
        while (__hip_atomic_load(bar, __ATOMIC_RELAXED, __HIP_MEMORY_SCOPE_AGENT) < NBLK) {
            __builtin_amdgcn_s_sleep(8);
        }
        __threadfence();
    }
    __syncthreads();

    if (wv == 0) {
        // ================= WAVE 0: pure updater =================
        const int n = n0 + ln;
        float v, I0, I1, bb, aa, bd0, bd1, as0, as1, vth, vrst, vrest, cm, tau, msk;
        v = v0[n]; I0 = Ia0[2 * n]; I1 = Ia0[2 * n + 1];
        bb = b_in[n]; vth = vth_in[n]; vrst = vrst_in[n]; vrest = vrest_in[n];
        cm = cm_in[n]; tau = tau_in[n]; msk = mask_in[n];
        aa  = (float)exp((double)(-1.0f / tau));
        bd0 = (float)exp((double)(-k_in[2 * n]));
        bd1 = (float)exp((double)(-k_in[2 * n + 1]));
        as0 = asc_in[2 * n]; as1 = asc_in[2 * n + 1];

        for (int t = 0; t < TSTEPS; ++t) {
            float xt = x_seq[(size_t)t * BN + n];       // overlaps flag wait

            {   // lanes spin on one flag each (8 flags, lanes mirror mod 8)
                const unsigned want = (unsigned)(t + 1);
                const unsigned* fp = &flags[ln & 7];
                while (ld_flag(fp) < want) {}
            }
            const float* pf = &partials[t & 3][0][0];
            float l0 = pf[ln],        l1 = pf[64 + ln],  l2 = pf[128 + ln], l3 = pf[192 + ln];
            float l4 = pf[256 + ln],  l5 = pf[320 + ln], l6 = pf[384 + ln], l7 = pf[448 + ln];
            float lin = ((l0 + l1) + (l2 + l3)) + ((l4 + l5) + (l6 + l7));
            float xx = (xt + bb) + lin;
            float Isum = I0 + I1;
            float vinf = vrest + (tau * (xx + Isum)) / cm;
            float vp = vinf + (v - vinf) * aa;
            float uu = (vp - vth) / (vth - vrst);
            float s = (uu > 0.0f) ? msk : 0.0f;
            u64 bal = __ballot(s != 0.0f);              // bit l = neuron n0+l
            u64 tagw = ((u64)(t + 1)) << 32;
            u64* dst = sbuf + ((size_t)((t + 1) & 1) * NBLK + blk) * ESTRIDE;
            if (ln < 2) st_agent(dst + ln, tagw | (u64)(unsigned)(bal >> (32 * ln)));
            float vpost = vp - (vp - vrst) * s;         // HARD_RESET
            I0 = I0 * bd0 + as0 * s;
            I1 = I1 * bd1 + as1 * s;
            v = vpost;
            out_s[(size_t)t * BN + n] = s;
            out_v[(size_t)t * BN + n] = vpost;
        }
        out_vf[n] = v;
        out_if[2 * n] = I0;
        out_if[2 * n + 1] = I1;
    } else {
        // ============ WAVES 1..8: arrival-driven gather ============
        const int gw = wv - 1;
        const int e = ln >> 3;                  // entry within this wave's 8
        const int sub = ln & 7;                 // lane's role: word sub>>2
        const int wsel = sub >> 2;              // tagged word 0 or 1
        const int entry = gw * 8 + e;
        const float* wcol = wT + n0 + ln;       // + col*BN per column
        const float* wrow = w + (size_t)(n0 + ln) * BN;  // fallback path

        for (int t = 0; t < TSTEPS; ++t) {
            const u64* p = sbuf + ((size_t)(t & 1) * NBLK + entry) * ESTRIDE + wsel;
            const unsigned want = (unsigned)t;
            u64 ev = 0;
            bool got = false;
            unsigned pend = 0xFFu;              // this wave's 8 entries
            float a0 = 0.f, a1 = 0.f, a2 = 0.f, a3 = 0.f,
                  a4 = 0.f, a5 = 0.f, a6 = 0.f, a7 = 0.f;

            while (pend) {
                if (!got) {
                    ev = ld_agent(p);
                    got = ((unsigned)(ev >> 32) == want);
                }
                const u64 rm = __ballot(got);
                const unsigned evlo = (unsigned)ev;

#define PROC_ENTRY(E2, ACC)                                                     \
                if ((pend & (1u << E2)) &&                                      \
                    (((rm >> (8 * E2)) & 0xFFull) == 0xFFull)) {                \
                    pend &= ~(1u << E2);                                        \
                    unsigned mlo = (unsigned)__shfl((int)evlo, 8 * E2);         \
                    unsigned mhi = (unsigned)__shfl((int)evlo, 8 * E2 + 4);     \
                    u64 mm = ((u64)mhi << 32) | (u64)mlo;                       \
                    const int cb = ((gw << 3) + E2) << 6;                       \
                    while (mm) {                                                \
                        int bp = (int)__builtin_ctzll(mm);                      \
                        mm &= mm - 1;                                           \
                        if (TR) ACC += wcol[(size_t)(cb + bp) << 12];           \
                        else    ACC += wrow[cb + bp] * mask_in[cb + bp];        \
                    }                                                           \
                }

                PROC_ENTRY(0, a0)
                PROC_ENTRY(1, a1)
                PROC_ENTRY(2, a2)
                PROC_ENTRY(3, a3)
                PROC_ENTRY(4, a4)
                PROC_ENTRY(5, a5)
                PROC_ENTRY(6, a6)
                PROC_ENTRY(7, a7)
#undef PROC_ENTRY
            }

            // fixed 8-leaf combine (independent of arrival order)
            float lp = ((a0 + a1) + (a2 + a3)) + ((a4 + a5) + (a6 + a7));
            partials[t & 3][gw][ln] = lp;
            __builtin_amdgcn_s_waitcnt(0);      // ensure LDS write visible order
            if (ln == 0) st_flag(&flags[gw], (unsigned)(t + 1));  // release
        }
    }
}

extern "C" void kernel_launch(void* const* d_in, const int* in_sizes, int n_in,
                              void* d_out, int out_size, void* d_ws, size_t ws_size,
                              hipStream_t stream)
{
    const float* x_seq = (const float*)d_in[0];
    const float* w     = (const float*)d_in[1];
    const float* b     = (const float*)d_in[2];
    const float* v0    = (const float*)d_in[3];
    const float* Ia0   = (const float*)d_in[4];
    const float* vth   = (const float*)d_in[5];
    const float* vrst  = (const float*)d_in[6];
    const float* vrest = (const float*)d_in[7];
    const float* cm    = (const float*)d_in[8];
    const float* tau   = (const float*)d_in[9];
    const float* k     = (const float*)d_in[10];
    const float* asc   = (const float*)d_in[11];
    const float* mask  = (const float*)d_in[12];

    float* out_s  = (float*)d_out;
    float* out_v  = out_s + (size_t)TSTEPS * BN;
    float* out_vf = out_v + (size_t)TSTEPS * BN;
    float* out_if = out_vf + BN;

    // mailbox: 2 parities x 64 blocks x 128-B line = 16 KiB
    const size_t mb_bytes = (size_t)2 * NBLK * ESTRIDE * sizeof(u64);
    u64* sbuf     = (u64*)d_ws;
    unsigned* bar = (unsigned*)((char*)d_ws + mb_bytes);
    float* wT     = (float*)((char*)d_ws + mb_bytes + 256);

    const size_t need = mb_bytes + 256 + (size_t)BN * BN * sizeof(float);
    const bool tr = (ws_size >= need);

    // zero mailbox tags + barrier counter (inside graph -> resets every replay)
    hipMemsetAsync(d_ws, 0, mb_bytes + 256, stream);

    if (tr) {
        glif_kernel<true><<<NBLK, NTHR, 0, stream>>>(
            x_seq, w, b, v0, Ia0, vth, vrst, vrest, cm, tau, k, asc, mask,
            out_s, out_v, out_vf, out_if, sbuf, bar, wT);
    } else {
        glif_kernel<false><<<NBLK, NTHR, 0, stream>>>(
            x_seq, w, b, v0, Ia0, vth, vrst, vrest, cm, tau, k, asc, mask,
            out_s, out_v, out_vf, out_if, sbuf, bar, (float*)w);
    }
}

// Round 9
// 1664.368 us; speedup vs baseline: 3.0079x; 3.0079x over previous
//
#include <hip/hip_runtime.h>
#include <math.h>

#define TSTEPS 512
#define BN 4096
#define NBLK 64
#define NTHR 576      // 9 waves: wave 0 = updater, waves 1..8 = gather waves
#define NPB 64        // neurons per block
#define NGW 8         // gather waves
#define ESTRIDE 16    // u64s per mailbox entry: one 128-B line per block

typedef unsigned long long u64;

__device__ __forceinline__ u64 ld_agent(const u64* p) {
    return __hip_atomic_load(p, __ATOMIC_RELAXED, __HIP_MEMORY_SCOPE_AGENT);
}
// Publish via atomic EXCHANGE, not plain store: RMWs execute at the L3
// coherence point, so the new tag is immediately visible to remote-XCD
// pollers. A plain store lingers dirty in the producer XCD's L2 until lazy
// write-back (theory: the ~2.5us/step hidden cost of R2..R6).
__device__ __forceinline__ void pub_agent(u64* p, u64 v) {
    (void)__hip_atomic_exchange(p, v, __ATOMIC_RELAXED, __HIP_MEMORY_SCOPE_AGENT);
}
__device__ __forceinline__ void st_flag(unsigned* p, unsigned v) {
    __hip_atomic_store(p, v, __ATOMIC_RELEASE, __HIP_MEMORY_SCOPE_WORKGROUP);
}
__device__ __forceinline__ unsigned ld_flag(const unsigned* p) {
    return __hip_atomic_load(p, __ATOMIC_ACQUIRE, __HIP_MEMORY_SCOPE_WORKGROUP);
}

// Persistent kernel, 64 blocks x 576 threads (9 waves). Structure = R6 (best):
//  wave 0   : pure updater. Spins on 8 LDS flags, combines partials (fixed
//             tree), updates 64 neurons, publishes 2 tagged mailbox words
//             (via atomic exchange -- the round's one mechanism change).
//  waves 1-8: free-running gather waves, no block barrier in the step loop.
//             Poll own mailbox entries (2 loads in flight), 64-lane scan ->
//             compacted column list, pipelined float4 gather of mask-scaled
//             wT, shfl reduce, write partials into 4-deep LDS ring, release
//             monotonic LDS flag.
// Determinism: fixed word/bit/tree order everywhere.
template<bool TR>
__global__ __launch_bounds__(NTHR, 1)
void glif_kernel(const float* __restrict__ x_seq, const float* __restrict__ w,
                 const float* __restrict__ b_in, const float* __restrict__ v0,
                 const float* __restrict__ Ia0, const float* __restrict__ vth_in,
                 const float* __restrict__ vrst_in, const float* __restrict__ vrest_in,
                 const float* __restrict__ cm_in, const float* __restrict__ tau_in,
                 const float* __restrict__ k_in, const float* __restrict__ asc_in,
                 const float* __restrict__ mask_in,
                 float* __restrict__ out_s, float* __restrict__ out_v,
                 float* __restrict__ out_vf, float* __restrict__ out_if,
                 u64* __restrict__ sbuf, unsigned* __restrict__ bar,
                 float* __restrict__ wT)
{
    __shared__ float    tile[64][65];          // transpose staging (phase 0)
    __shared__ int      wlist[NGW][512];       // per-gather-wave column lists
    __shared__ float4   partials[4][NGW][16];  // 4-deep ring of GEMV partials
    __shared__ unsigned flags[NGW];            // monotonic step tags

    const int blk = blockIdx.x;
    const int tid = threadIdx.x;
    const int n0 = blk * NPB;
    const int wv = tid >> 6;                   // wave 0..8
    const int ln = tid & 63;

    // ---- Phase 0: transpose w -> wT, folding mask into columns
    if (TR) {
        for (int tt = 0; tt < 64; ++tt) {
            int tile_id = blk + tt * NBLK;     // 4096 tiles of 64x64
            int ti = tile_id >> 6, tj = tile_id & 63;
            if (tid < 512) {
                int c = tid & 63, r0 = tid >> 6;
#pragma unroll
                for (int rr = 0; rr < 8; ++rr) {
                    int r = r0 + rr * 8;
                    tile[r][c] = w[(size_t)(ti * 64 + r) * BN + tj * 64 + c];
                }
            }
            __syncthreads();
            if (tid < 512) {
                int rw = tid & 63, c0 = tid >> 6;
#pragma unroll
                for (int cc = 0; cc < 8; ++cc) {
                    int cw = c0 + cc * 8;
                    float mcol = mask_in[tj * 64 + cw];
                    wT[(size_t)(tj * 64 + cw) * BN + ti * 64 + rw] = tile[rw][cw] * mcol;
                }
            }
            __syncthreads();
        }
    }

    if (tid < NGW) flags[tid] = 0;

    // ---- single grid barrier: wT complete before step loop
    __syncthreads();
    if (tid == 0) {
        __threadfence();
        __hip_atomic_fetch_add(bar, 1u, __ATOMIC_ACQ_REL, __HIP_MEMORY_SCOPE_AGENT);
        while (__hip_atomic_load(bar, __ATOMIC_RELAXED, __HIP_MEMORY_SCOPE_AGENT) < NBLK) {
            __builtin_amdgcn_s_sleep(8);
        }
        __threadfence();
    }
    __syncthreads();

    if (wv == 0) {
        // ================= WAVE 0: pure updater =================
        const int n = n0 + ln;
        float v, I0, I1, bb, aa, bd0, bd1, as0, as1, vth, vrst, vrest, cm, tau, msk;
        v = v0[n]; I0 = Ia0[2 * n]; I1 = Ia0[2 * n + 1];
        bb = b_in[n]; vth = vth_in[n]; vrst = vrst_in[n]; vrest = vrest_in[n];
        cm = cm_in[n]; tau = tau_in[n]; msk = mask_in[n];
        aa  = (float)exp((double)(-1.0f / tau));
        bd0 = (float)exp((double)(-k_in[2 * n]));
        bd1 = (float)exp((double)(-k_in[2 * n + 1]));
        as0 = asc_in[2 * n]; as1 = asc_in[2 * n + 1];

        for (int t = 0; t < TSTEPS; ++t) {
            float xt = x_seq[(size_t)t * BN + n];       // overlaps flag wait

            {   // lanes spin on one flag each (8 flags, lanes mirror mod 8)
                const unsigned want = (unsigned)(t + 1);
                const unsigned* fp = &flags[ln & 7];
                while (ld_flag(fp) < want) {}
            }
            const float* pf = reinterpret_cast<const float*>(&partials[t & 3][0][0]);
            float l0 = pf[ln],        l1 = pf[64 + ln],  l2 = pf[128 + ln], l3 = pf[192 + ln];
            float l4 = pf[256 + ln],  l5 = pf[320 + ln], l6 = pf[384 + ln], l7 = pf[448 + ln];
            float lin = ((l0 + l1) + (l2 + l3)) + ((l4 + l5) + (l6 + l7));
            float xx = (xt + bb) + lin;
            float Isum = I0 + I1;
            float vinf = vrest + (tau * (xx + Isum)) / cm;
            float vp = vinf + (v - vinf) * aa;
            float uu = (vp - vth) / (vth - vrst);
            float s = (uu > 0.0f) ? msk : 0.0f;
            u64 bal = __ballot(s != 0.0f);              // bit l = neuron n0+l
            u64 tagw = ((u64)(t + 1)) << 32;
            u64* dst = sbuf + ((size_t)((t + 1) & 1) * NBLK + blk) * ESTRIDE;
            if (ln < 2) pub_agent(dst + ln, tagw | (u64)(unsigned)(bal >> (32 * ln)));
            float vpost = vp - (vp - vrst) * s;         // HARD_RESET
            I0 = I0 * bd0 + as0 * s;
            I1 = I1 * bd1 + as1 * s;
            v = vpost;
            out_s[(size_t)t * BN + n] = s;
            out_v[(size_t)t * BN + n] = vpost;
        }
        out_vf[n] = v;
        out_if[2 * n] = I0;
        out_if[2 * n + 1] = I1;
    } else {
        // ================= WAVES 1..8: free-running gather =================
        const int gw = wv - 1;
        const int e = ln >> 3;                  // entry within this wave's 8
        const int sub = ln & 7;                 // byte 0..7 of the 64-bit mask
        const int wsel = sub >> 2;              // tagged word 0 or 1
        const int bshift = 8 * (sub & 3);
        const int entry = gw * 8 + e;
        const int cbase = (entry << 6) + (sub << 3);
        const int cslot = ln >> 4, l16 = ln & 15;  // 4 cols/round, 16 lanes/col
        const float* wb4 = wT + n0 + l16 * 4;

        for (int t = 0; t < TSTEPS; ++t) {
            // ---- busy-spin poll, 2 loads in flight
            const u64* p = sbuf + ((size_t)(t & 1) * NBLK + entry) * ESTRIDE + wsel;
            const unsigned want = (unsigned)t;
            u64 ev;
            for (;;) {
                u64 A = ld_agent(p);
                u64 B = ld_agent(p);
                if ((unsigned)(A >> 32) == want) { ev = A; break; }
                if ((unsigned)(B >> 32) == want) { ev = B; break; }
            }
            unsigned byte = ((unsigned)ev >> bshift) & 0xFFu;

            // ---- in-wave compaction (fixed order => deterministic)
            int c = __popc(byte);
            int x = c;
#pragma unroll
            for (int d = 1; d < 64; d <<= 1) {
                int y = __shfl_up(x, d);
                if (ln >= d) x += y;
            }
            const int kw = __shfl(x, 63);
            int base = x - c;
            while (byte) { int bp = __ffs(byte) - 1; byte &= byte - 1; wlist[gw][base++] = cbase + bp; }

            // ---- pipelined gather-GEMV over this wave's columns
            if (TR) {
                float4 acc = make_float4(0.f, 0.f, 0.f, 0.f);
                const int R = (kw + 3) >> 2;     // rounds of 4 columns
                for (int r = 0; r < R; r += 8) {
#pragma unroll
                    for (int u = 0; u < 8; ++u) {
                        int idx = (r + u) * 4 + cslot;
                        bool pg = idx < kw;
                        int j = wlist[gw][pg ? idx : 0];
                        float m = pg ? 1.0f : 0.0f;
                        const float4 wvv = *reinterpret_cast<const float4*>(wb4 + ((size_t)j << 12));
                        acc.x = fmaf(wvv.x, m, acc.x);
                        acc.y = fmaf(wvv.y, m, acc.y);
                        acc.z = fmaf(wvv.z, m, acc.z);
                        acc.w = fmaf(wvv.w, m, acc.w);
                    }
                }
#pragma unroll
                for (int d = 16; d < 64; d <<= 1) {
                    acc.x += __shfl_xor(acc.x, d);
                    acc.y += __shfl_xor(acc.y, d);
                    acc.z += __shfl_xor(acc.z, d);
                    acc.w += __shfl_xor(acc.w, d);
                }
                if (ln < 16) partials[t & 3][gw][ln] = acc;
            } else {
                float accs = 0.f;
                const float* wrow = w + (size_t)(n0 + ln) * BN;
                for (int i = 0; i < kw; ++i) {
                    int j = wlist[gw][i];
                    accs = fmaf(wrow[j], mask_in[j], accs);
                }
                reinterpret_cast<float*>(&partials[t & 3][gw][0])[ln] = accs;
            }
            if (ln == 0) st_flag(&flags[gw], (unsigned)(t + 1));  // release
        }
    }
}

extern "C" void kernel_launch(void* const* d_in, const int* in_sizes, int n_in,
                              void* d_out, int out_size, void* d_ws, size_t ws_size,
                              hipStream_t stream)
{
    const float* x_seq = (const float*)d_in[0];
    const float* w     = (const float*)d_in[1];
    const float* b     = (const float*)d_in[2];
    const float* v0    = (const float*)d_in[3];
    const float* Ia0   = (const float*)d_in[4];
    const float* vth   = (const float*)d_in[5];
    const float* vrst  = (const float*)d_in[6];
    const float* vrest = (const float*)d_in[7];
    const float* cm    = (const float*)d_in[8];
    const float* tau   = (const float*)d_in[9];
    const float* k     = (const float*)d_in[10];
    const float* asc   = (const float*)d_in[11];
    const float* mask  = (const float*)d_in[12];

    float* out_s  = (float*)d_out;
    float* out_v  = out_s + (size_t)TSTEPS * BN;
    float* out_vf = out_v + (size_t)TSTEPS * BN;
    float* out_if = out_vf + BN;

    // mailbox: 2 parities x 64 blocks x 128-B line = 16 KiB
    const size_t mb_bytes = (size_t)2 * NBLK * ESTRIDE * sizeof(u64);
    u64* sbuf     = (u64*)d_ws;
    unsigned* bar = (unsigned*)((char*)d_ws + mb_bytes);
    float* wT     = (float*)((char*)d_ws + mb_bytes + 256);

    const size_t need = mb_bytes + 256 + (size_t)BN * BN * sizeof(float);
    const bool tr = (ws_size >= need);

    // zero mailbox tags + barrier counter (inside graph -> resets every replay)
    hipMemsetAsync(d_ws, 0, mb_bytes + 256, stream);

    if (tr) {
        glif_kernel<true><<<NBLK, NTHR, 0, stream>>>(
            x_seq, w, b, v0, Ia0, vth, vrst, vrest, cm, tau, k, asc, mask,
            out_s, out_v, out_vf, out_if, sbuf, bar, wT);
    } else {
        glif_kernel<false><<<NBLK, NTHR, 0, stream>>>(
            x_seq, w, b, v0, Ia0, vth, vrst, vrest, cm, tau, k, asc, mask,
            out_s, out_v, out_vf, out_if, sbuf, bar, (float*)w);
    }
}